// Round 2
// baseline (296.618 us; speedup 1.0000x reference)
//
#include <hip/hip_runtime.h>

typedef __attribute__((ext_vector_type(8))) short short8;
typedef __attribute__((ext_vector_type(4))) float f32x4;

__device__ __forceinline__ unsigned short f2bf(float f){
  unsigned u = __float_as_uint(f);
  return (unsigned short)((u + 0x7fffu + ((u >> 16) & 1u)) >> 16);
}
__device__ __forceinline__ float bf2f(unsigned short b){
  return __uint_as_float(((unsigned)b) << 16);
}
__device__ __forceinline__ float sigf(float v){
  return __builtin_amdgcn_rcpf(1.0f + __builtin_amdgcn_exp2f(v * -1.44269504088896341f));
}
__device__ __forceinline__ float tanhf_fast(float v){
  float e = __builtin_amdgcn_exp2f(v * 2.88539008177792681f);
  return (e - 1.0f) * __builtin_amdgcn_rcpf(e + 1.0f);
}

// ---------------- weight conversion: fp32 -> bf16 in ws ----------------
// wgt layout (u16 elems):
//   whhT_b [384*128]  @0
//   W1b    [128*96]   @49152   (96 = 68 padded to 96, zeros)
//   W2b    [128*128]  @61440
//   Wf1b   [256*1152] @77824
//   Wf2b   [128*256]  @372736
//   Wf3b   [64*128]   @405504
//   whhN_b [192*64]   @413696
//   total 425984 elems
__global__ __launch_bounds__(256) void k_prep(
    const float* __restrict__ Whh_t, const float* __restrict__ W1,
    const float* __restrict__ W2,    const float* __restrict__ Wf1,
    const float* __restrict__ Wf2,   const float* __restrict__ Wf3,
    const float* __restrict__ Whh_n,
    unsigned short* __restrict__ wgt)
{
  int i = blockIdx.x * 256 + threadIdx.x;
  if (i < 49152){ wgt[i] = f2bf(Whh_t[i]); return; }
  i -= 49152;
  if (i < 12288){ int r = i / 96, c = i % 96;
    wgt[49152 + i] = (c < 68) ? f2bf(W1[r*68 + c]) : (unsigned short)0; return; }
  i -= 12288;
  if (i < 16384){ wgt[61440 + i] = f2bf(W2[i]); return; }
  i -= 16384;
  if (i < 294912){ wgt[77824 + i] = f2bf(Wf1[i]); return; }
  i -= 294912;
  if (i < 32768){ wgt[372736 + i] = f2bf(Wf2[i]); return; }
  i -= 32768;
  if (i < 8192){ wgt[405504 + i] = f2bf(Wf3[i]); return; }
  i -= 8192;
  if (i < 12288){ wgt[413696 + i] = f2bf(Whh_n[i]); return; }
}

// ---------------- fused GRU (neighbor + target) + sector pooling ----------------
// blocks 0..31: target GRU (64 batches each, H=128) -> combined[:,0:128]
// blocks 32..2079: neighbor GRU (one batch b = blk-32, 64 neighbors, H=64)
//                  + sector pooling -> sf[b*8+s][96]
__global__ __launch_bounds__(256) void k_gru(
    const float* __restrict__ ttraj, const float* __restrict__ ntraj,
    const float* __restrict__ rang,  const float* __restrict__ nmask,
    const float* __restrict__ Wih_t, const float* __restrict__ bih_t, const float* __restrict__ bhh_t,
    const float* __restrict__ Wih_n,
    const float* __restrict__ bih_n, const float* __restrict__ bhh_n,
    const unsigned short* __restrict__ wgt,
    unsigned short* __restrict__ combined,       // [2048][1152] bf16
    unsigned short* __restrict__ sf)             // [16384][96] bf16
{
  __shared__ char smem[44288];
  const int tid = threadIdx.x;
  const int w = tid >> 6, u = (tid >> 4) & 3, c = tid & 15;
  const unsigned short* whhT_b = wgt;            // [384][128]
  const unsigned short* whhN_b = wgt + 413696;   // [192][64]

  if (blockIdx.x >= 32){
    // ======== neighbor path ========
    const int b = blockIdx.x - 32;
    unsigned short* whh  = (unsigned short*)smem;                       // [192][72]
    unsigned short* hall = (unsigned short*)(smem + 27648);             // 4 x [16][72]
    unsigned short* hb   = hall + w * 1152;
    float* xs   = (float*)(smem + 36864);                               // [64][16]
    float* wm   = (float*)(smem + 40960);                               // [64][8]
    float* dv   = (float*)(smem + 43008);                               // dist/vx/vy [3][64]
    float* sidv = (float*)(smem + 43776);                               // [64]
    float* sect = (float*)(smem + 44032);                               // [8][8]

    // copy pre-converted bf16 Whh_n into padded LDS [192][72]
    for (int i = tid; i < 1536; i += 256){
      int r = i >> 3, cg = (i & 7) * 8;
      *(short8*)&whh[r*72 + cg] = *(const short8*)&whhN_b[r*64 + cg];
    }
    ((float4*)xs)[tid] = ((const float4*)(ntraj + (size_t)b * 1024))[tid];
    wm[tid] = 0.0f; wm[256 + tid] = 0.0f;
    __syncthreads();

    // per-lane gate constants (gate col g = gt*16 + c)
    float wr0[4],wr1[4],br_[4],wz0[4],wz1[4],bz_[4],wn0[4],wn1[4],bi_[4],bh_[4];
#pragma unroll
    for (int gt = 0; gt < 4; ++gt){
      int g = gt*16 + c;
      wr0[gt]=Wih_n[g*2];  wr1[gt]=Wih_n[g*2+1];  br_[gt]=bih_n[g]+bhh_n[g];
      int gz = 64+g;  wz0[gt]=Wih_n[gz*2]; wz1[gt]=Wih_n[gz*2+1]; bz_[gt]=bih_n[gz]+bhh_n[gz];
      int gn = 128+g; wn0[gt]=Wih_n[gn*2]; wn1[gt]=Wih_n[gn*2+1]; bi_[gt]=bih_n[gn]; bh_[gt]=bhh_n[gn];
    }
    float hcur[4][4];
#pragma unroll
    for (int gt=0; gt<4; ++gt)
#pragma unroll
      for (int q=0; q<4; ++q) hcur[gt][q] = 0.0f;

    for (int st = 0; st < 8; ++st){
      f32x4 acc[12];
      if (st > 0){
        short8 a0 = *(short8*)&hb[c*72 + u*8];
        short8 a1 = *(short8*)&hb[c*72 + 32 + u*8];
#pragma unroll
        for (int nt = 0; nt < 12; ++nt){
          short8 b0 = *(short8*)&whh[(nt*16+c)*72 + u*8];
          short8 b1 = *(short8*)&whh[(nt*16+c)*72 + 32 + u*8];
          f32x4 t = {0.f,0.f,0.f,0.f};
          t = __builtin_amdgcn_mfma_f32_16x16x32_bf16(a0, b0, t, 0,0,0);
          acc[nt] = __builtin_amdgcn_mfma_f32_16x16x32_bf16(a1, b1, t, 0,0,0);
        }
      } else {
#pragma unroll
        for (int nt = 0; nt < 12; ++nt) acc[nt] = (f32x4){0.f,0.f,0.f,0.f};
      }
      float xq0[4], xq1[4];
#pragma unroll
      for (int q=0; q<4; ++q){
        int sq = w*16 + u*4 + q;
        xq0[q] = xs[sq*16 + st*2];
        xq1[q] = xs[sq*16 + st*2 + 1];
      }
#pragma unroll
      for (int gt=0; gt<4; ++gt){
#pragma unroll
        for (int q=0; q<4; ++q){
          float x0 = xq0[q], x1 = xq1[q];
          float rp = wr0[gt]*x0 + wr1[gt]*x1 + br_[gt] + acc[gt][q];
          float zp = wz0[gt]*x0 + wz1[gt]*x1 + bz_[gt] + acc[4+gt][q];
          float r = sigf(rp), z = sigf(zp);
          float hn = acc[8+gt][q] + bh_[gt];
          float pn = wn0[gt]*x0 + wn1[gt]*x1 + bi_[gt] + r*hn;
          float n = tanhf_fast(pn);
          float hnew = n + z*(hcur[gt][q] - n);
          hcur[gt][q] = hnew;
          hb[(u*4+q)*72 + gt*16 + c] = f2bf(hnew);
        }
      }
    }
    __syncthreads();

    // ---- sector pooling ----
    if (tid < 64){
      int n = tid;
      float m   = nmask[(size_t)b*64 + n];
      float ang = rang[(size_t)b*64 + n];
      float tx = ttraj[(size_t)b*16 + 14], ty = ttraj[(size_t)b*16 + 15];
      float px = xs[n*16+14], py = xs[n*16+15];
      float vx = px - xs[n*16+12], vy = py - xs[n*16+13];
      float dx = px - tx, dy = py - ty;
      float dist = __builtin_amdgcn_sqrtf(dx*dx + dy*dy);
      int sid = (int)(ang / 0.78539816339744830962f);
      sid = sid < 0 ? 0 : (sid > 7 ? 7 : sid);
      bool valid = m > 0.0f;
      float wv = valid ? __builtin_amdgcn_exp2f(dist * -0.14426950408889634f) : 0.0f;
      wm[n*8 + sid] = wv;
      dv[n]      = valid ? dist : 0.0f;
      dv[64+n]   = valid ? vx   : 0.0f;
      dv[128+n]  = valid ? vy   : 0.0f;
      sidv[n]    = valid ? (float)sid : -1.0f;
    }
    __syncthreads();
    if (tid < 8){
      int s = tid;
      float cnt=0.f, sd=0.f, sx=0.f, sy=0.f, sw=0.f;
      for (int n=0; n<64; ++n){
        if (sidv[n] == (float)s){
          cnt += 1.f; sd += dv[n]; sx += dv[64+n]; sy += dv[128+n]; sw += wm[n*8+s];
        }
      }
      float inv = (cnt > 0.f) ? __builtin_amdgcn_rcpf(cnt) : 0.f;
      sect[s*8+0] = cnt;
      sect[s*8+1] = sd * inv;
      sect[s*8+2] = sx * inv;
      sect[s*8+3] = sy * inv;
      sect[s*8+4] = __builtin_amdgcn_rcpf(sw + 1e-8f);
    }
    __syncthreads();
#pragma unroll
    for (int rep = 0; rep < 2; ++rep){
      int p = tid + rep*256;
      int s = p >> 6, h = p & 63;
      float a = 0.f;
      for (int n = 0; n < 64; ++n){
        float wmv = wm[n*8 + s];
        float nf  = bf2f(hall[(n>>4)*1152 + (n&15)*72 + h]);
        a += wmv * nf;
      }
      sf[((size_t)b*8 + s)*96 + 4 + h] = f2bf(a * sect[s*8+4]);
    }
    if (tid < 32){
      int s = tid >> 2, cc = tid & 3;
      sf[((size_t)b*8 + s)*96 + cc] = f2bf(sect[s*8+cc]);
    }
    if (tid < 224){
      int s = tid / 28, cc = 68 + tid % 28;
      sf[((size_t)b*8 + s)*96 + cc] = 0;
    }
  } else {
    // ======== target path ========
    const int tb = blockIdx.x;
    unsigned short* hb = (unsigned short*)smem + w * 2176;   // [16][136] per wave
    float* xs  = (float*)(smem + 17408);                     // [64][16]
    float* wih = (float*)(smem + 21504);                     // [384][2]
    float* bc  = (float*)(smem + 24576);                     // [384]
    float* bhn = (float*)(smem + 26112);                     // [128]

    ((float4*)xs)[tid] = ((const float4*)(ttraj + (size_t)tb*1024))[tid];
    for (int i = tid; i < 768; i += 256) wih[i] = Wih_t[i];
    for (int i = tid; i < 384; i += 256) bc[i] = bih_t[i] + ((i < 256) ? bhh_t[i] : 0.f);
    for (int i = tid; i < 128; i += 256) bhn[i] = bhh_t[256 + i];
    __syncthreads();

    for (int st = 0; st < 8; ++st){
      f32x4 acc[24];
      if (st > 0){
        short8 a0 = *(short8*)&hb[c*136 + u*8];
        short8 a1 = *(short8*)&hb[c*136 + 32 + u*8];
        short8 a2 = *(short8*)&hb[c*136 + 64 + u*8];
        short8 a3 = *(short8*)&hb[c*136 + 96 + u*8];
#pragma unroll
        for (int nt = 0; nt < 24; ++nt){
          const unsigned short* wp = whhT_b + (nt*16+c)*128 + u*8;
          f32x4 t = {0.f,0.f,0.f,0.f};
          t = __builtin_amdgcn_mfma_f32_16x16x32_bf16(a0, *(const short8*)(wp),     t, 0,0,0);
          t = __builtin_amdgcn_mfma_f32_16x16x32_bf16(a1, *(const short8*)(wp+32),  t, 0,0,0);
          t = __builtin_amdgcn_mfma_f32_16x16x32_bf16(a2, *(const short8*)(wp+64),  t, 0,0,0);
          acc[nt] = __builtin_amdgcn_mfma_f32_16x16x32_bf16(a3, *(const short8*)(wp+96), t, 0,0,0);
        }
      } else {
#pragma unroll
        for (int nt = 0; nt < 24; ++nt) acc[nt] = (f32x4){0.f,0.f,0.f,0.f};
      }
      float xq0[4], xq1[4];
#pragma unroll
      for (int q=0; q<4; ++q){
        int sq = w*16 + u*4 + q;
        xq0[q] = xs[sq*16 + st*2]; xq1[q] = xs[sq*16 + st*2 + 1];
      }
#pragma unroll
      for (int gt = 0; gt < 8; ++gt){
        int g = gt*16 + c;
        float Wr0=wih[g*2],        Wr1=wih[g*2+1],        BR=bc[g];
        float Wz0=wih[(128+g)*2],  Wz1=wih[(128+g)*2+1],  BZ=bc[128+g];
        float Wn0=wih[(256+g)*2],  Wn1=wih[(256+g)*2+1],  BI=bc[256+g], BH=bhn[g];
#pragma unroll
        for (int q=0; q<4; ++q){
          float x0 = xq0[q], x1 = xq1[q];
          float rp = Wr0*x0 + Wr1*x1 + BR + acc[gt][q];
          float zp = Wz0*x0 + Wz1*x1 + BZ + acc[8+gt][q];
          float r = sigf(rp), z = sigf(zp);
          float hn = acc[16+gt][q] + BH;
          float pn = Wn0*x0 + Wn1*x1 + BI + r*hn;
          float n = tanhf_fast(pn);
          float hold = (st == 0) ? 0.f : bf2f(hb[(u*4+q)*136 + g]);
          float hnew = n + z*(hold - n);
          if (st < 7){
            hb[(u*4+q)*136 + g] = f2bf(hnew);
          } else {
            int row = tb*64 + w*16 + u*4 + q;
            combined[(size_t)row*1152 + g] = f2bf(hnew);
          }
        }
      }
    }
  }
}

// ---------------- MLP1/MLP2 over (b,s) rows: sf -> enc part of combined ----------------
__global__ __launch_bounds__(256) void k_mlp12(
    const unsigned short* __restrict__ sf,    // [16384][96]
    const unsigned short* __restrict__ wgt,
    const float* __restrict__ b1, const float* __restrict__ b2,
    unsigned short* __restrict__ combined)
{
  __shared__ char smem[18432];
  unsigned short* hb = (unsigned short*)smem + (threadIdx.x >> 6) * 2176;  // [16][136]/wave
  float* b1s = (float*)(smem + 17408);
  float* b2s = b1s + 128;
  const unsigned short* w1b = wgt + 49152;
  const unsigned short* w2b = wgt + 61440;
  const int tid = threadIdx.x, w = tid >> 6, u = (tid >> 4) & 3, c = tid & 15;
  if (tid < 128){ b1s[tid] = b1[tid]; b2s[tid] = b2[tid]; }
  __syncthreads();
  const int rowb = blockIdx.x * 64 + w * 16;

  f32x4 acc[8];
#pragma unroll
  for (int nt=0; nt<8; ++nt) acc[nt] = (f32x4){0.f,0.f,0.f,0.f};
#pragma unroll
  for (int kc=0; kc<3; ++kc){
    short8 a = *(const short8*)&sf[(size_t)(rowb + c)*96 + kc*32 + u*8];
#pragma unroll
    for (int nt=0; nt<8; ++nt){
      short8 bb = *(const short8*)&w1b[(nt*16+c)*96 + kc*32 + u*8];
      acc[nt] = __builtin_amdgcn_mfma_f32_16x16x32_bf16(a, bb, acc[nt], 0,0,0);
    }
  }
#pragma unroll
  for (int nt=0; nt<8; ++nt){
    float bias = b1s[nt*16+c];
#pragma unroll
    for (int q=0; q<4; ++q){
      float v = acc[nt][q] + bias; v = v > 0.f ? v : 0.f;
      hb[(u*4+q)*136 + nt*16 + c] = f2bf(v);
    }
  }
  f32x4 acc2[8];
#pragma unroll
  for (int nt=0; nt<8; ++nt) acc2[nt] = (f32x4){0.f,0.f,0.f,0.f};
#pragma unroll
  for (int kc=0; kc<4; ++kc){
    short8 a = *(short8*)&hb[c*136 + kc*32 + u*8];
#pragma unroll
    for (int nt=0; nt<8; ++nt){
      short8 bb = *(const short8*)&w2b[(nt*16+c)*128 + kc*32 + u*8];
      acc2[nt] = __builtin_amdgcn_mfma_f32_16x16x32_bf16(a, bb, acc2[nt], 0,0,0);
    }
  }
#pragma unroll
  for (int nt=0; nt<8; ++nt){
    float bias = b2s[nt*16+c];
#pragma unroll
    for (int q=0; q<4; ++q){
      float v = acc2[nt][q] + bias; v = v > 0.f ? v : 0.f;
      int r = rowb + u*4 + q;
      combined[(size_t)(r >> 3)*1152 + 128 + (r & 7)*128 + nt*16 + c] = f2bf(v);
    }
  }
}

// ---------------- head: f1 -> f2 -> f3 -> LayerNorm -> out ----------------
__global__ __launch_bounds__(256) void k_head(
    const unsigned short* __restrict__ combined,
    const unsigned short* __restrict__ wgt,
    const float* __restrict__ bf1, const float* __restrict__ bf2, const float* __restrict__ bf3,
    const float* __restrict__ lng, const float* __restrict__ lnb,
    float* __restrict__ out)
{
  __shared__ char smem[53504];
  const int tid = threadIdx.x, w = tid >> 6, u = (tid >> 4) & 3, c = tid & 15;
  unsigned short* f1b = (unsigned short*)smem + w * 4224;              // [16][264]/wave
  unsigned short* f2b = (unsigned short*)(smem + 33792) + w * 2176;    // [16][136]/wave
  float* bf1s = (float*)(smem + 51200); float* bf2s = bf1s + 256; float* bf3s = bf2s + 128;
  float* lngs = bf3s + 64; float* lnbs = lngs + 64;
  const unsigned short* wf1b = wgt + 77824;
  const unsigned short* wf2b = wgt + 372736;
  const unsigned short* wf3b = wgt + 405504;
  bf1s[tid] = bf1[tid];
  if (tid < 128) bf2s[tid] = bf2[tid];
  if (tid < 64){ bf3s[tid] = bf3[tid]; lngs[tid] = lng[tid]; lnbs[tid] = lnb[tid]; }
  __syncthreads();
  const int rowb = blockIdx.x * 64 + w * 16;

  f32x4 acc[16];
#pragma unroll
  for (int nt=0; nt<16; ++nt) acc[nt] = (f32x4){0.f,0.f,0.f,0.f};
  for (int kc=0; kc<36; ++kc){
    short8 a = *(const short8*)&combined[(size_t)(rowb + c)*1152 + kc*32 + u*8];
#pragma unroll
    for (int nt=0; nt<16; ++nt){
      short8 bb = *(const short8*)&wf1b[(size_t)(nt*16+c)*1152 + kc*32 + u*8];
      acc[nt] = __builtin_amdgcn_mfma_f32_16x16x32_bf16(a, bb, acc[nt], 0,0,0);
    }
  }
#pragma unroll
  for (int nt=0; nt<16; ++nt){
    float bias = bf1s[nt*16+c];
#pragma unroll
    for (int q=0; q<4; ++q){
      float v = acc[nt][q] + bias; v = v > 0.f ? v : 0.f;
      f1b[(u*4+q)*264 + nt*16 + c] = f2bf(v);
    }
  }
  f32x4 acc2[8];
#pragma unroll
  for (int nt=0; nt<8; ++nt) acc2[nt] = (f32x4){0.f,0.f,0.f,0.f};
#pragma unroll
  for (int kc=0; kc<8; ++kc){
    short8 a = *(short8*)&f1b[c*264 + kc*32 + u*8];
#pragma unroll
    for (int nt=0; nt<8; ++nt){
      short8 bb = *(const short8*)&wf2b[(nt*16+c)*256 + kc*32 + u*8];
      acc2[nt] = __builtin_amdgcn_mfma_f32_16x16x32_bf16(a, bb, acc2[nt], 0,0,0);
    }
  }
#pragma unroll
  for (int nt=0; nt<8; ++nt){
    float bias = bf2s[nt*16+c];
#pragma unroll
    for (int q=0; q<4; ++q){
      float v = acc2[nt][q] + bias; v = v > 0.f ? v : 0.f;
      f2b[(u*4+q)*136 + nt*16 + c] = f2bf(v);
    }
  }
  f32x4 acc3[4];
#pragma unroll
  for (int nt=0; nt<4; ++nt) acc3[nt] = (f32x4){0.f,0.f,0.f,0.f};
#pragma unroll
  for (int kc=0; kc<4; ++kc){
    short8 a = *(short8*)&f2b[c*136 + kc*32 + u*8];
#pragma unroll
    for (int nt=0; nt<4; ++nt){
      short8 bb = *(const short8*)&wf3b[(nt*16+c)*128 + kc*32 + u*8];
      acc3[nt] = __builtin_amdgcn_mfma_f32_16x16x32_bf16(a, bb, acc3[nt], 0,0,0);
    }
  }
  float v[4][4];
#pragma unroll
  for (int nt=0; nt<4; ++nt){
    float bias = bf3s[nt*16+c];
#pragma unroll
    for (int q=0; q<4; ++q){
      float t = acc3[nt][q] + bias; v[nt][q] = t > 0.f ? t : 0.f;
    }
  }
#pragma unroll
  for (int q=0; q<4; ++q){
    float p = v[0][q] + v[1][q] + v[2][q] + v[3][q];
    p += __shfl_xor(p, 1); p += __shfl_xor(p, 2); p += __shfl_xor(p, 4); p += __shfl_xor(p, 8);
    float mu = p * 0.015625f;
    float d0 = v[0][q]-mu, d1 = v[1][q]-mu, d2 = v[2][q]-mu, d3 = v[3][q]-mu;
    float p2 = d0*d0 + d1*d1 + d2*d2 + d3*d3;
    p2 += __shfl_xor(p2, 1); p2 += __shfl_xor(p2, 2); p2 += __shfl_xor(p2, 4); p2 += __shfl_xor(p2, 8);
    float rstd = __builtin_amdgcn_rsqf(p2 * 0.015625f + 1e-5f);
    int row = rowb + u*4 + q;
#pragma unroll
    for (int nt=0; nt<4; ++nt){
      int col = nt*16 + c;
      out[(size_t)row*64 + col] = (v[nt][q] - mu) * rstd * lngs[col] + lnbs[col];
    }
  }
}

extern "C" void kernel_launch(void* const* d_in, const int* in_sizes, int n_in,
                              void* d_out, int out_size, void* d_ws, size_t ws_size,
                              hipStream_t stream)
{
  const float* ttraj = (const float*)d_in[0];
  const float* ntraj = (const float*)d_in[1];
  const float* rang  = (const float*)d_in[2];
  const float* nmask = (const float*)d_in[3];
  const float* Wih_t = (const float*)d_in[4];
  const float* Whh_t = (const float*)d_in[5];
  const float* bih_t = (const float*)d_in[6];
  const float* bhh_t = (const float*)d_in[7];
  const float* Wih_n = (const float*)d_in[8];
  const float* Whh_n = (const float*)d_in[9];
  const float* bih_n = (const float*)d_in[10];
  const float* bhh_n = (const float*)d_in[11];
  const float* W1  = (const float*)d_in[12];
  const float* b1  = (const float*)d_in[13];
  const float* W2  = (const float*)d_in[14];
  const float* b2  = (const float*)d_in[15];
  const float* Wf1 = (const float*)d_in[16];
  const float* bf1 = (const float*)d_in[17];
  const float* Wf2 = (const float*)d_in[18];
  const float* bf2 = (const float*)d_in[19];
  const float* Wf3 = (const float*)d_in[20];
  const float* bf3 = (const float*)d_in[21];
  const float* lng = (const float*)d_in[22];
  const float* lnb = (const float*)d_in[23];

  char* ws = (char*)d_ws;
  unsigned short* combined = (unsigned short*)ws;                  // [2048][1152] bf16
  unsigned short* sf       = (unsigned short*)(ws + 5242880);      // [16384][96] bf16
  unsigned short* wgt      = (unsigned short*)(ws + 8388608);      // bf16 weights

  hipLaunchKernelGGL(k_prep, dim3(1664), dim3(256), 0, stream,
                     Whh_t, W1, W2, Wf1, Wf2, Wf3, Whh_n, wgt);
  hipLaunchKernelGGL(k_gru, dim3(2080), dim3(256), 0, stream,
                     ttraj, ntraj, rang, nmask, Wih_t, bih_t, bhh_t,
                     Wih_n, bih_n, bhh_n, wgt, combined, sf);
  hipLaunchKernelGGL(k_mlp12, dim3(256), dim3(256), 0, stream, sf, wgt, b1, b2, combined);
  hipLaunchKernelGGL(k_head, dim3(32), dim3(256), 0, stream,
                     combined, wgt, bf1, bf2, bf3, lng, lnb, (float*)d_out);
}